// Round 17
// baseline (439.624 us; speedup 1.0000x reference)
//
#include <hip/hip_runtime.h>

#define B_ 16
#define C_ 64
#define H_ 128
#define W_ 256
#define K_ 9
#define KDIM_ (K_*C_)            // 576

typedef __attribute__((ext_vector_type(8))) short short8_t;
typedef __attribute__((ext_vector_type(4))) float f32x4;

static __device__ __forceinline__ float bf2f(unsigned short u) {
  union { unsigned int i; float f; } v; v.i = ((unsigned int)u) << 16; return v.f;
}
static __device__ __forceinline__ unsigned short f2bf(float f) {
  union { float f; unsigned int i; } v; v.f = f;
  unsigned int r = v.i + 0x7FFF + ((v.i >> 16) & 1);   // RNE
  return (unsigned short)(r >> 16);
}

// async global->LDS, 16B per lane; lds base wave-uniform, lanes fill +lane*16
static __device__ __forceinline__ void gload_lds16(const void* g, void* l) {
  __builtin_amdgcn_global_load_lds(
      (const __attribute__((address_space(1))) unsigned int*)g,
      (__attribute__((address_space(3))) unsigned int*)l, 16, 0, 0);
}

// All 4 weight tensors [co][ci][kk] fp32 -> A2 chunk layout (16B chunk = 8
// consecutive k for one co): A2[((k>>3)*64+co)*8 + (k&7)], k = kk*64+ci.
// Also zeroes the 1KB zeropage.
__global__ __launch_bounds__(256) void prep_w_all(const float* __restrict__ w0,
                                                  const float* __restrict__ w1,
                                                  const float* __restrict__ w2,
                                                  const float* __restrict__ w3,
                                                  unsigned short* __restrict__ A2,
                                                  float* __restrict__ ZPf) {
  if (blockIdx.y == 0 && blockIdx.x == 0) ZPf[threadIdx.x] = 0.f;  // 1KB zeropage
  int idx = blockIdx.x * 256 + threadIdx.x;
  if (idx >= C_ * KDIM_) return;
  int which = blockIdx.y;
  const float* w = (which == 0) ? w0 : (which == 1) ? w1 : (which == 2) ? w2 : w3;
  unsigned short* out = A2 + (size_t)which * (C_ * KDIM_);
  int co = idx / KDIM_, k = idx % KDIM_;
  int ci = k & 63, kk = k >> 6;
  out[((size_t)(k >> 3) * 64 + co) * 8 + (k & 7)] =
      f2bf(w[((size_t)co * C_ + ci) * K_ + kk]);
}

// fp32 NCHW -> bf16 ci-minor [b][h][w][ci]
__global__ __launch_bounds__(256) void transpose_in(const float* __restrict__ x,
                                                    unsigned short* __restrict__ Xt) {
  __shared__ float tile[64][65];
  const int w0 = blockIdx.x * 64, h = blockIdx.y, b = blockIdx.z;
  const int t = threadIdx.x;
#pragma unroll
  for (int rep = 0; rep < 16; ++rep) {
    int idx = rep * 256 + t;
    int ci = idx >> 6, wl = idx & 63;
    tile[ci][wl] = x[((size_t)(b * C_ + ci) * H_ + h) * W_ + w0 + wl];
  }
  __syncthreads();
#pragma unroll
  for (int rep = 0; rep < 8; ++rep) {
    int idx = rep * 256 + t;
    int wl = idx >> 5, cp = idx & 31;
    unsigned v = (unsigned)f2bf(tile[cp*2][wl]) | ((unsigned)f2bf(tile[cp*2+1][wl]) << 16);
    *(unsigned*)(Xt + ((size_t)(b * H_ + h) * W_ + w0 + wl) * C_ + cp * 2) = v;
  }
}

// ===== conv6: square-tile MFMA conv on [b][R][Q][ci], conv along Q =====
// Grid 256 (1 block/CU, LDS 143KB), 4 waves. Full A (72KB) in LDS; X staged
// as 256-position super-tiles, double-buffered (34KB each, swizzled: LDS slot
// s of row r holds chunk s^(r&7) via pre-swizzled global source).
// QLEN=256: super-tile = 1 row. QLEN=128: super-tile = 2 rows as 2 strips.
// Wave wv owns 64 positions x all 64 co (4x4 MFMA tiles): per K-step
// 4 A ds_reads + 4 X ds_reads feed 16 MFMAs.
template<int QLEN>
__global__ __launch_bounds__(256, 1) void conv6(const unsigned short* __restrict__ X,
                                                unsigned short* __restrict__ Y,
                                                const unsigned short* __restrict__ A2,
                                                const float* __restrict__ bias,
                                                const unsigned short* __restrict__ ZP) {
  constexpr int SEGROWS = 256 / QLEN;              // 1 or 2 strips
  constexpr int NG      = (256 + 8 * SEGROWS) / 8; // 33 or 34 groups of 1KB
  __shared__ __align__(16) char lds[73728 + 2 * 34816];
  char* Alds  = lds;
  char* xbuf0 = lds + 73728;
  char* xbuf1 = lds + 73728 + 34816;

  const int t = threadIdx.x;
  const int lane = t & 63, wv = t >> 6;
  const int llo = lane & 15, lhi = lane >> 4;

  // ---- A -> LDS: 72 x 1KB groups, 18 per wave ----
#pragma unroll
  for (int i = 0; i < 18; ++i) {
    int m = wv + i * 4;
    gload_lds16(A2 + (size_t)m * 512 + lane * 8, Alds + m * 1024);
  }

  // stage super-tile u into dst
  auto stageX = [&](char* dst, int u) {
#pragma unroll
    for (int i = 0; i < 9; ++i) {
      int gl = wv + i * 4;
      if (gl < NG) {
        int strip = (SEGROWS == 2 && gl >= 17) ? 1 : 0;
        int gg = gl - strip * 17;
        int r = gg * 8 + (lane >> 3);            // row within strip
        int slot = lane & 7;
        int chunk = slot ^ (r & 7);
        int q = r - 4;
        int rowId = (SEGROWS == 1) ? u : u * 2 + strip;
        const void* src = ((unsigned)q < (unsigned)QLEN)
            ? (const void*)(X + (size_t)rowId * (QLEN * 64) + (size_t)q * 64 + chunk * 8)
            : (const void*)(ZP + slot * 8);
        gload_lds16(src, dst + strip * 17408 + gg * 1024);
      }
    }
  };

  float4 bv[4];
#pragma unroll
  for (int j = 0; j < 4; ++j) bv[j] = *(const float4*)(bias + j * 16 + lhi * 4);

  const int stripoff = (SEGROWS == 1) ? 0 : (wv >> 1) * 17408;
  const int posbase  = (SEGROWS == 1) ? wv * 64 : (wv & 1) * 64;

  const int u0 = blockIdx.x * 8;
  stageX(xbuf0, u0);
  __syncthreads();

  for (int tt = 0; tt < 8; ++tt) {
    const int u = u0 + tt;
    char* cur = (tt & 1) ? xbuf1 : xbuf0;
    char* nxt = (tt & 1) ? xbuf0 : xbuf1;
    if (tt < 7) stageX(nxt, u + 1);              // issue BEFORE compute

    const char* xb = cur + stripoff;
    f32x4 acc[4][4];
#pragma unroll
    for (int i = 0; i < 4; ++i)
#pragma unroll
      for (int j = 0; j < 4; ++j) { f32x4 z = {0.f,0.f,0.f,0.f}; acc[i][j] = z; }

#pragma unroll
    for (int step = 0; step < 18; ++step) {
      const int kk = step >> 1;
      const int cg = (step & 1) * 4 + lhi;
      short8_t a[4], f[4];
#pragma unroll
      for (int j = 0; j < 4; ++j)
        a[j] = *(const short8_t*)(Alds + step * 4096 + lhi * 1024 + j * 256 + llo * 16);
#pragma unroll
      for (int i = 0; i < 4; ++i) {
        int r = posbase + i * 16 + llo + kk;
        f[i] = *(const short8_t*)(xb + r * 128 + ((cg ^ (r & 7)) << 4));
      }
#pragma unroll
      for (int i = 0; i < 4; ++i)
#pragma unroll
        for (int j = 0; j < 4; ++j)
          acc[i][j] = __builtin_amdgcn_mfma_f32_16x16x32_bf16(a[j], f[i], acc[i][j], 0, 0, 0);
    }

    // epilogue: +bias, pack 4 consecutive co, 8B stores
    const int outRow = (SEGROWS == 1) ? u : u * 2 + (wv >> 1);
    const size_t rowbase = (size_t)outRow * (QLEN * 64);
#pragma unroll
    for (int j = 0; j < 4; ++j) {
#pragma unroll
      for (int i = 0; i < 4; ++i) {
        const int q = posbase + i * 16 + llo;
        float v0 = acc[i][j][0] + bv[j].x;
        float v1 = acc[i][j][1] + bv[j].y;
        float v2 = acc[i][j][2] + bv[j].z;
        float v3 = acc[i][j][3] + bv[j].w;
        unsigned lo, hi;
        asm("v_cvt_pk_bf16_f32 %0, %1, %2" : "=v"(lo) : "v"(v0), "v"(v1));
        asm("v_cvt_pk_bf16_f32 %0, %1, %2" : "=v"(hi) : "v"(v2), "v"(v3));
        uint2 ov; ov.x = lo; ov.y = hi;
        *(uint2*)(Y + rowbase + (size_t)q * 64 + j * 16 + lhi * 4) = ov;
      }
    }
    __syncthreads();
  }
}

// ===== scan along OUTER dim P of [b][P][Q][ci], 4 ci/thread, depth-8 =====
// TRANS=1: write result transposed to [b][Q][P][ci] (outT) instead of in-place.
template<int PLEN, int QLEN, int REV, int TRANS>
__global__ __launch_bounds__(128) void scan_o4(unsigned short* __restrict__ conv,
                                               const unsigned short* __restrict__ prev,
                                               unsigned short* __restrict__ outT) {
  int idx = blockIdx.x * 128 + threadIdx.x;     // B * QLEN * 16
  int cq = idx & 15;
  int q  = (idx >> 4) % QLEN;
  int b  = idx / (16 * QLEN);
  const ptrdiff_t dp = (REV ? -1 : 1) * (ptrdiff_t)(QLEN * 64);
  const int p0 = REV ? PLEN - 1 : 0;
  size_t off = ((size_t)(b * PLEN + p0) * QLEN + q) * 64 + cq * 4;
  size_t offT = 0; ptrdiff_t dpT = 0;
  if (TRANS) {
    offT = ((size_t)(b * QLEN + q) * PLEN + p0) * 64 + cq * 4;
    dpT = (REV ? -1 : 1) * (ptrdiff_t)64;
  }
  uint2 pv = *(const uint2*)(prev + off);
  if (TRANS) *(uint2*)(outT + offT) = pv; else *(uint2*)(conv + off) = pv;
  float y0 = bf2f((unsigned short)pv.x), y1 = bf2f((unsigned short)(pv.x >> 16));
  float y2 = bf2f((unsigned short)pv.y), y3 = bf2f((unsigned short)(pv.y >> 16));
  uint2 c[8];
#pragma unroll
  for (int j = 0; j < 8; ++j) c[j] = *(const uint2*)(conv + off + (ptrdiff_t)(j + 1) * dp);
  for (int base = 1; base < PLEN; base += 8) {
#pragma unroll
    for (int j = 0; j < 8; ++j) {
      int s = base + j;
      if (s < PLEN) {
        off += dp;
        if (TRANS) offT += dpT;
        y0 = fmaxf(bf2f((unsigned short)c[j].x) + y0, 0.f);
        y1 = fmaxf(bf2f((unsigned short)(c[j].x >> 16)) + y1, 0.f);
        y2 = fmaxf(bf2f((unsigned short)c[j].y) + y2, 0.f);
        y3 = fmaxf(bf2f((unsigned short)(c[j].y >> 16)) + y3, 0.f);
        uint2 ov;
        ov.x = (unsigned)f2bf(y0) | ((unsigned)f2bf(y1) << 16);
        ov.y = (unsigned)f2bf(y2) | ((unsigned)f2bf(y3) << 16);
        if (TRANS) *(uint2*)(outT + offT) = ov; else *(uint2*)(conv + off) = ov;
        if (s + 8 < PLEN) c[j] = *(const uint2*)(conv + off + 8 * dp);
      }
    }
  }
}

// ===== scan4_out: sweep-4 scan (rev along w) on [b][w][h][ci] writing fp32
// NCHW output DIRECTLY, replacing scan + transpose_out (saves 134MB traffic).
// Fix vs R15's failed version: results for 16 consecutive w are batched in
// registers per ci-plane and flushed as 4 aligned float4 (full 64B lines,
// back-to-back from one thread -> no partial-line eviction / amplification).
// Thread = (b, h, ci-pair); 2 planes x 16 f32 buffers, all indices static.
__global__ __launch_bounds__(128) void scan4_out(const unsigned short* __restrict__ conv,
                                                 const unsigned short* __restrict__ prev,
                                                 float* __restrict__ out) {
  int idx = blockIdx.x * 128 + threadIdx.x;     // B * H * 32
  int cp = idx & 31;                             // ci pair (2 ci)
  int h  = (idx >> 5) & (H_ - 1);
  int b  = idx >> 12;
  const ptrdiff_t dp = -(ptrdiff_t)(H_ * 64);    // w descending
  size_t off = ((size_t)(b * W_ + (W_ - 1)) * H_ + h) * 64 + cp * 2;
  const size_t ob0 = ((size_t)(b * C_ + cp * 2) * H_ + h) * W_;
  const size_t ob1 = ob0 + (size_t)H_ * W_;

  unsigned pv = *(const unsigned*)(prev + off);
  float y0 = bf2f((unsigned short)pv), y1 = bf2f((unsigned short)(pv >> 16));
  float f0[16], f1[16];
  f0[15] = y0; f1[15] = y1;                      // w=255 passthrough

  unsigned c[8];
#pragma unroll
  for (int j = 0; j < 8; ++j)
    c[j] = *(const unsigned*)(conv + off + (ptrdiff_t)(j + 1) * dp);

  for (int batch = 0; batch < 16; ++batch) {
#pragma unroll
    for (int k = 0; k < 16; ++k) {
      if (batch == 0 && k == 0) continue;        // slot 15 already filled
      off += dp;
      unsigned cv = c[(k - 1) & 7];              // static: 16 ≡ 0 mod 8
      y0 = fmaxf(bf2f((unsigned short)cv) + y0, 0.f);
      y1 = fmaxf(bf2f((unsigned short)(cv >> 16)) + y1, 0.f);
      f0[15 - k] = y0; f1[15 - k] = y1;
      int s = batch * 16 + k;
      if (s + 8 < W_) c[(k - 1) & 7] = *(const unsigned*)(conv + off + 8 * dp);
    }
    const int wbase = (15 - batch) * 16;
#pragma unroll
    for (int m = 0; m < 4; ++m) {
      float4 v0; v0.x = f0[4*m]; v0.y = f0[4*m+1]; v0.z = f0[4*m+2]; v0.w = f0[4*m+3];
      float4 v1; v1.x = f1[4*m]; v1.y = f1[4*m+1]; v1.z = f1[4*m+2]; v1.w = f1[4*m+3];
      *(float4*)(out + ob0 + wbase + 4*m) = v0;
      *(float4*)(out + ob1 + wbase + 4*m) = v1;
    }
  }
}

extern "C" void kernel_launch(void* const* d_in, const int* in_sizes, int n_in,
                              void* d_out, int out_size, void* d_ws, size_t ws_size,
                              hipStream_t stream) {
  const float* x    = (const float*)d_in[0];
  const float* w_ud = (const float*)d_in[1];
  const float* b_ud = (const float*)d_in[2];
  const float* w_du = (const float*)d_in[3];
  const float* b_du = (const float*)d_in[4];
  const float* w_lr = (const float*)d_in[5];
  const float* b_lr = (const float*)d_in[6];
  const float* w_rl = (const float*)d_in[7];
  const float* b_rl = (const float*)d_in[8];

  // ws: A[0,64M) Bb[64M,128M) Cc[128M,192M) A2 @192M, zeropage @192M+1M
  unsigned short* A  = (unsigned short*)d_ws;
  unsigned short* Bb = (unsigned short*)((char*)d_ws + 67108864);
  unsigned short* Cc = (unsigned short*)((char*)d_ws + 134217728);
  unsigned short* A2 = (unsigned short*)((char*)d_ws + 201326592);
  unsigned short* ZP = (unsigned short*)((char*)d_ws + 202375168);
  unsigned short* A2_ud = A2 + 0 * (C_ * KDIM_);
  unsigned short* A2_du = A2 + 1 * (C_ * KDIM_);
  unsigned short* A2_lr = A2 + 2 * (C_ * KDIM_);
  unsigned short* A2_rl = A2 + 3 * (C_ * KDIM_);

  dim3 pg((C_ * KDIM_ + 255) / 256, 4);
  prep_w_all<<<pg, 256, 0, stream>>>(w_ud, w_du, w_lr, w_rl, A2, (float*)ZP);

  transpose_in<<<dim3(4, H_, B_), 256, 0, stream>>>(x, A);

  // sweep 1 (ud): conv along W on [b][h][w][ci]; scan fwd along h
  conv6<W_><<<256, 256, 0, stream>>>(A, Bb, A2_ud, b_ud, ZP);
  scan_o4<H_, W_, 0, 0><<<512, 128, 0, stream>>>(Bb, A, nullptr);

  // sweep 2 (du): conv along W; scan rev along h, WRITE TRANSPOSED -> [b][w][h][ci]
  conv6<W_><<<256, 256, 0, stream>>>(Bb, Cc, A2_du, b_du, ZP);
  scan_o4<H_, W_, 1, 1><<<512, 128, 0, stream>>>(Cc, Bb, A);

  // sweep 3 (lr): conv along H (inner dim of flipped layout); scan fwd along w
  conv6<H_><<<256, 256, 0, stream>>>(A, Bb, A2_lr, b_lr, ZP);
  scan_o4<W_, H_, 0, 0><<<256, 128, 0, stream>>>(Bb, A, nullptr);

  // sweep 4 (rl): conv along H; scan rev along w, fp32 NCHW direct (batched)
  conv6<H_><<<256, 256, 0, stream>>>(Bb, Cc, A2_rl, b_rl, ZP);
  scan4_out<<<512, 128, 0, stream>>>(Cc, Bb, (float*)d_out);
}

// Round 18
// 365.323 us; speedup vs baseline: 1.2034x; 1.2034x over previous
//
#include <hip/hip_runtime.h>

#define B_ 16
#define C_ 64
#define H_ 128
#define W_ 256
#define K_ 9
#define KDIM_ (K_*C_)            // 576

typedef __attribute__((ext_vector_type(8))) short short8_t;
typedef __attribute__((ext_vector_type(4))) float f32x4;

static __device__ __forceinline__ float bf2f(unsigned short u) {
  union { unsigned int i; float f; } v; v.i = ((unsigned int)u) << 16; return v.f;
}
static __device__ __forceinline__ unsigned short f2bf(float f) {
  union { float f; unsigned int i; } v; v.f = f;
  unsigned int r = v.i + 0x7FFF + ((v.i >> 16) & 1);   // RNE
  return (unsigned short)(r >> 16);
}

// async global->LDS, 16B per lane; lds base wave-uniform, lanes fill +lane*16
static __device__ __forceinline__ void gload_lds16(const void* g, void* l) {
  __builtin_amdgcn_global_load_lds(
      (const __attribute__((address_space(1))) unsigned int*)g,
      (__attribute__((address_space(3))) unsigned int*)l, 16, 0, 0);
}

// All 4 weight tensors [co][ci][kk] fp32 -> A2 chunk layout (16B chunk = 8
// consecutive k for one co): A2[((k>>3)*64+co)*8 + (k&7)], k = kk*64+ci.
// Also zeroes the 1KB zeropage.
__global__ __launch_bounds__(256) void prep_w_all(const float* __restrict__ w0,
                                                  const float* __restrict__ w1,
                                                  const float* __restrict__ w2,
                                                  const float* __restrict__ w3,
                                                  unsigned short* __restrict__ A2,
                                                  float* __restrict__ ZPf) {
  if (blockIdx.y == 0 && blockIdx.x == 0) ZPf[threadIdx.x] = 0.f;  // 1KB zeropage
  int idx = blockIdx.x * 256 + threadIdx.x;
  if (idx >= C_ * KDIM_) return;
  int which = blockIdx.y;
  const float* w = (which == 0) ? w0 : (which == 1) ? w1 : (which == 2) ? w2 : w3;
  unsigned short* out = A2 + (size_t)which * (C_ * KDIM_);
  int co = idx / KDIM_, k = idx % KDIM_;
  int ci = k & 63, kk = k >> 6;
  out[((size_t)(k >> 3) * 64 + co) * 8 + (k & 7)] =
      f2bf(w[((size_t)co * C_ + ci) * K_ + kk]);
}

// fp32 NCHW -> bf16 ci-minor [b][h][w][ci]
__global__ __launch_bounds__(256) void transpose_in(const float* __restrict__ x,
                                                    unsigned short* __restrict__ Xt) {
  __shared__ float tile[64][65];
  const int w0 = blockIdx.x * 64, h = blockIdx.y, b = blockIdx.z;
  const int t = threadIdx.x;
#pragma unroll
  for (int rep = 0; rep < 16; ++rep) {
    int idx = rep * 256 + t;
    int ci = idx >> 6, wl = idx & 63;
    tile[ci][wl] = x[((size_t)(b * C_ + ci) * H_ + h) * W_ + w0 + wl];
  }
  __syncthreads();
#pragma unroll
  for (int rep = 0; rep < 8; ++rep) {
    int idx = rep * 256 + t;
    int wl = idx >> 5, cp = idx & 31;
    unsigned v = (unsigned)f2bf(tile[cp*2][wl]) | ((unsigned)f2bf(tile[cp*2+1][wl]) << 16);
    *(unsigned*)(Xt + ((size_t)(b * H_ + h) * W_ + w0 + wl) * C_ + cp * 2) = v;
  }
}

// [b][w][h][ci] bf16 -> fp32 NCHW (final output, after the layout flip)
__global__ __launch_bounds__(256) void transpose_out_wh(const unsigned short* __restrict__ F,
                                                        float* __restrict__ out) {
  __shared__ float tile[64][65];   // [wl][ci]
  const int w0 = blockIdx.x * 64, h = blockIdx.y, b = blockIdx.z;
  const int t = threadIdx.x;
#pragma unroll
  for (int rep = 0; rep < 4; ++rep) {
    int idx = rep * 256 + t;
    int cp = idx & 15, wl = idx >> 4;
    uint2 v = *(const uint2*)(F + ((size_t)(b * W_ + w0 + wl) * H_ + h) * C_ + cp * 4);
    tile[wl][cp*4+0] = bf2f((unsigned short)v.x);
    tile[wl][cp*4+1] = bf2f((unsigned short)(v.x >> 16));
    tile[wl][cp*4+2] = bf2f((unsigned short)v.y);
    tile[wl][cp*4+3] = bf2f((unsigned short)(v.y >> 16));
  }
  __syncthreads();
#pragma unroll
  for (int rep = 0; rep < 16; ++rep) {
    int idx = rep * 256 + t;
    int ci = idx >> 6, wl = idx & 63;
    out[((size_t)(b * C_ + ci) * H_ + h) * W_ + w0 + wl] = tile[wl][ci];
  }
}

// ===== conv6: square-tile MFMA conv on [b][R][Q][ci], conv along Q =====
// Grid 256 (1 block/CU, LDS 143KB), 4 waves. Full A (72KB) in LDS; X staged
// as 256-position super-tiles, double-buffered (34KB each, swizzled: LDS slot
// s of row r holds chunk s^(r&7) via pre-swizzled global source).
// QLEN=256: super-tile = 1 row. QLEN=128: super-tile = 2 rows as 2 strips.
// Wave wv owns 64 positions x all 64 co (4x4 MFMA tiles): per K-step
// 4 A ds_reads + 4 X ds_reads feed 16 MFMAs.
template<int QLEN>
__global__ __launch_bounds__(256, 1) void conv6(const unsigned short* __restrict__ X,
                                                unsigned short* __restrict__ Y,
                                                const unsigned short* __restrict__ A2,
                                                const float* __restrict__ bias,
                                                const unsigned short* __restrict__ ZP) {
  constexpr int SEGROWS = 256 / QLEN;              // 1 or 2 strips
  constexpr int NG      = (256 + 8 * SEGROWS) / 8; // 33 or 34 groups of 1KB
  __shared__ __align__(16) char lds[73728 + 2 * 34816];
  char* Alds  = lds;
  char* xbuf0 = lds + 73728;
  char* xbuf1 = lds + 73728 + 34816;

  const int t = threadIdx.x;
  const int lane = t & 63, wv = t >> 6;
  const int llo = lane & 15, lhi = lane >> 4;

  // ---- A -> LDS: 72 x 1KB groups, 18 per wave ----
#pragma unroll
  for (int i = 0; i < 18; ++i) {
    int m = wv + i * 4;
    gload_lds16(A2 + (size_t)m * 512 + lane * 8, Alds + m * 1024);
  }

  // stage super-tile u into dst
  auto stageX = [&](char* dst, int u) {
#pragma unroll
    for (int i = 0; i < 9; ++i) {
      int gl = wv + i * 4;
      if (gl < NG) {
        int strip = (SEGROWS == 2 && gl >= 17) ? 1 : 0;
        int gg = gl - strip * 17;
        int r = gg * 8 + (lane >> 3);            // row within strip
        int slot = lane & 7;
        int chunk = slot ^ (r & 7);
        int q = r - 4;
        int rowId = (SEGROWS == 1) ? u : u * 2 + strip;
        const void* src = ((unsigned)q < (unsigned)QLEN)
            ? (const void*)(X + (size_t)rowId * (QLEN * 64) + (size_t)q * 64 + chunk * 8)
            : (const void*)(ZP + slot * 8);
        gload_lds16(src, dst + strip * 17408 + gg * 1024);
      }
    }
  };

  float4 bv[4];
#pragma unroll
  for (int j = 0; j < 4; ++j) bv[j] = *(const float4*)(bias + j * 16 + lhi * 4);

  const int stripoff = (SEGROWS == 1) ? 0 : (wv >> 1) * 17408;
  const int posbase  = (SEGROWS == 1) ? wv * 64 : (wv & 1) * 64;

  const int u0 = blockIdx.x * 8;
  stageX(xbuf0, u0);
  __syncthreads();

  for (int tt = 0; tt < 8; ++tt) {
    const int u = u0 + tt;
    char* cur = (tt & 1) ? xbuf1 : xbuf0;
    char* nxt = (tt & 1) ? xbuf0 : xbuf1;
    if (tt < 7) stageX(nxt, u + 1);              // issue BEFORE compute

    const char* xb = cur + stripoff;
    f32x4 acc[4][4];
#pragma unroll
    for (int i = 0; i < 4; ++i)
#pragma unroll
      for (int j = 0; j < 4; ++j) { f32x4 z = {0.f,0.f,0.f,0.f}; acc[i][j] = z; }

#pragma unroll
    for (int step = 0; step < 18; ++step) {
      const int kk = step >> 1;
      const int cg = (step & 1) * 4 + lhi;
      short8_t a[4], f[4];
#pragma unroll
      for (int j = 0; j < 4; ++j)
        a[j] = *(const short8_t*)(Alds + step * 4096 + lhi * 1024 + j * 256 + llo * 16);
#pragma unroll
      for (int i = 0; i < 4; ++i) {
        int r = posbase + i * 16 + llo + kk;
        f[i] = *(const short8_t*)(xb + r * 128 + ((cg ^ (r & 7)) << 4));
      }
#pragma unroll
      for (int i = 0; i < 4; ++i)
#pragma unroll
        for (int j = 0; j < 4; ++j)
          acc[i][j] = __builtin_amdgcn_mfma_f32_16x16x32_bf16(a[j], f[i], acc[i][j], 0, 0, 0);
    }

    // epilogue: +bias, pack 4 consecutive co, 8B stores
    const int outRow = (SEGROWS == 1) ? u : u * 2 + (wv >> 1);
    const size_t rowbase = (size_t)outRow * (QLEN * 64);
#pragma unroll
    for (int j = 0; j < 4; ++j) {
#pragma unroll
      for (int i = 0; i < 4; ++i) {
        const int q = posbase + i * 16 + llo;
        float v0 = acc[i][j][0] + bv[j].x;
        float v1 = acc[i][j][1] + bv[j].y;
        float v2 = acc[i][j][2] + bv[j].z;
        float v3 = acc[i][j][3] + bv[j].w;
        unsigned lo, hi;
        asm("v_cvt_pk_bf16_f32 %0, %1, %2" : "=v"(lo) : "v"(v0), "v"(v1));
        asm("v_cvt_pk_bf16_f32 %0, %1, %2" : "=v"(hi) : "v"(v2), "v"(v3));
        uint2 ov; ov.x = lo; ov.y = hi;
        *(uint2*)(Y + rowbase + (size_t)q * 64 + j * 16 + lhi * 4) = ov;
      }
    }
    __syncthreads();
  }
}

// ===== scan along OUTER dim P of [b][P][Q][ci], 4 ci/thread, depth-16 =====
// TRANS=1: write result transposed to [b][Q][P][ci] (outT) instead of in-place.
template<int PLEN, int QLEN, int REV, int TRANS>
__global__ __launch_bounds__(128) void scan_o4(unsigned short* __restrict__ conv,
                                               const unsigned short* __restrict__ prev,
                                               unsigned short* __restrict__ outT) {
  int idx = blockIdx.x * 128 + threadIdx.x;     // B * QLEN * 16
  int cq = idx & 15;
  int q  = (idx >> 4) % QLEN;
  int b  = idx / (16 * QLEN);
  const ptrdiff_t dp = (REV ? -1 : 1) * (ptrdiff_t)(QLEN * 64);
  const int p0 = REV ? PLEN - 1 : 0;
  size_t off = ((size_t)(b * PLEN + p0) * QLEN + q) * 64 + cq * 4;
  size_t offT = 0; ptrdiff_t dpT = 0;
  if (TRANS) {
    offT = ((size_t)(b * QLEN + q) * PLEN + p0) * 64 + cq * 4;
    dpT = (REV ? -1 : 1) * (ptrdiff_t)64;
  }
  uint2 pv = *(const uint2*)(prev + off);
  if (TRANS) *(uint2*)(outT + offT) = pv; else *(uint2*)(conv + off) = pv;
  float y0 = bf2f((unsigned short)pv.x), y1 = bf2f((unsigned short)(pv.x >> 16));
  float y2 = bf2f((unsigned short)pv.y), y3 = bf2f((unsigned short)(pv.y >> 16));
  uint2 c[16];
#pragma unroll
  for (int j = 0; j < 16; ++j) c[j] = *(const uint2*)(conv + off + (ptrdiff_t)(j + 1) * dp);
  for (int base = 1; base < PLEN; base += 16) {
#pragma unroll
    for (int j = 0; j < 16; ++j) {
      int s = base + j;
      if (s < PLEN) {
        off += dp;
        if (TRANS) offT += dpT;
        y0 = fmaxf(bf2f((unsigned short)c[j].x) + y0, 0.f);
        y1 = fmaxf(bf2f((unsigned short)(c[j].x >> 16)) + y1, 0.f);
        y2 = fmaxf(bf2f((unsigned short)c[j].y) + y2, 0.f);
        y3 = fmaxf(bf2f((unsigned short)(c[j].y >> 16)) + y3, 0.f);
        uint2 ov;
        ov.x = (unsigned)f2bf(y0) | ((unsigned)f2bf(y1) << 16);
        ov.y = (unsigned)f2bf(y2) | ((unsigned)f2bf(y3) << 16);
        if (TRANS) *(uint2*)(outT + offT) = ov; else *(uint2*)(conv + off) = ov;
        if (s + 16 < PLEN) c[j] = *(const uint2*)(conv + off + 16 * dp);
      }
    }
  }
}

// ===== scan_o2: same scan, 2 ci/thread (uint) — doubles wave count for the
// QLEN=128 sweeps (3/4), whose 4-ci version had only 1 wave/SIMD. Depth-16.
template<int PLEN, int QLEN, int REV>
__global__ __launch_bounds__(128) void scan_o2(unsigned short* __restrict__ conv,
                                               const unsigned short* __restrict__ prev) {
  int idx = blockIdx.x * 128 + threadIdx.x;     // B * QLEN * 32
  int cp = idx & 31;
  int q  = (idx >> 5) % QLEN;
  int b  = idx / (32 * QLEN);
  const ptrdiff_t dp = (REV ? -1 : 1) * (ptrdiff_t)(QLEN * 64);
  const int p0 = REV ? PLEN - 1 : 0;
  size_t off = ((size_t)(b * PLEN + p0) * QLEN + q) * 64 + cp * 2;
  unsigned pv = *(const unsigned*)(prev + off);
  *(unsigned*)(conv + off) = pv;
  float y0 = bf2f((unsigned short)pv), y1 = bf2f((unsigned short)(pv >> 16));
  unsigned c[16];
#pragma unroll
  for (int j = 0; j < 16; ++j) c[j] = *(const unsigned*)(conv + off + (ptrdiff_t)(j + 1) * dp);
  for (int base = 1; base < PLEN; base += 16) {
#pragma unroll
    for (int j = 0; j < 16; ++j) {
      int s = base + j;
      if (s < PLEN) {
        off += dp;
        y0 = fmaxf(bf2f((unsigned short)c[j]) + y0, 0.f);
        y1 = fmaxf(bf2f((unsigned short)(c[j] >> 16)) + y1, 0.f);
        *(unsigned*)(conv + off) = (unsigned)f2bf(y0) | ((unsigned)f2bf(y1) << 16);
        if (s + 16 < PLEN) c[j] = *(const unsigned*)(conv + off + 16 * dp);
      }
    }
  }
}

extern "C" void kernel_launch(void* const* d_in, const int* in_sizes, int n_in,
                              void* d_out, int out_size, void* d_ws, size_t ws_size,
                              hipStream_t stream) {
  const float* x    = (const float*)d_in[0];
  const float* w_ud = (const float*)d_in[1];
  const float* b_ud = (const float*)d_in[2];
  const float* w_du = (const float*)d_in[3];
  const float* b_du = (const float*)d_in[4];
  const float* w_lr = (const float*)d_in[5];
  const float* b_lr = (const float*)d_in[6];
  const float* w_rl = (const float*)d_in[7];
  const float* b_rl = (const float*)d_in[8];

  // ws: A[0,64M) Bb[64M,128M) Cc[128M,192M) A2 @192M, zeropage @192M+1M
  unsigned short* A  = (unsigned short*)d_ws;
  unsigned short* Bb = (unsigned short*)((char*)d_ws + 67108864);
  unsigned short* Cc = (unsigned short*)((char*)d_ws + 134217728);
  unsigned short* A2 = (unsigned short*)((char*)d_ws + 201326592);
  unsigned short* ZP = (unsigned short*)((char*)d_ws + 202375168);
  unsigned short* A2_ud = A2 + 0 * (C_ * KDIM_);
  unsigned short* A2_du = A2 + 1 * (C_ * KDIM_);
  unsigned short* A2_lr = A2 + 2 * (C_ * KDIM_);
  unsigned short* A2_rl = A2 + 3 * (C_ * KDIM_);

  dim3 pg((C_ * KDIM_ + 255) / 256, 4);
  prep_w_all<<<pg, 256, 0, stream>>>(w_ud, w_du, w_lr, w_rl, A2, (float*)ZP);

  transpose_in<<<dim3(4, H_, B_), 256, 0, stream>>>(x, A);

  // sweep 1 (ud): conv along W on [b][h][w][ci]; scan fwd along h
  conv6<W_><<<256, 256, 0, stream>>>(A, Bb, A2_ud, b_ud, ZP);
  scan_o4<H_, W_, 0, 0><<<512, 128, 0, stream>>>(Bb, A, nullptr);

  // sweep 2 (du): conv along W; scan rev along h, WRITE TRANSPOSED -> [b][w][h][ci]
  conv6<W_><<<256, 256, 0, stream>>>(Bb, Cc, A2_du, b_du, ZP);
  scan_o4<H_, W_, 1, 1><<<512, 128, 0, stream>>>(Cc, Bb, A);

  // sweep 3 (lr): conv along H (inner dim of flipped layout); scan fwd along w
  conv6<H_><<<256, 256, 0, stream>>>(A, Bb, A2_lr, b_lr, ZP);
  scan_o2<W_, H_, 0><<<512, 128, 0, stream>>>(Bb, A);

  // sweep 4 (rl): conv along H; scan rev along w
  conv6<H_><<<256, 256, 0, stream>>>(Bb, Cc, A2_rl, b_rl, ZP);
  scan_o2<W_, H_, 1><<<512, 128, 0, stream>>>(Cc, Bb);

  transpose_out_wh<<<dim3(4, H_, B_), 256, 0, stream>>>(Cc, (float*)d_out);
}

// Round 19
// 356.428 us; speedup vs baseline: 1.2334x; 1.0250x over previous
//
#include <hip/hip_runtime.h>

#define B_ 16
#define C_ 64
#define H_ 128
#define W_ 256
#define K_ 9
#define KDIM_ (K_*C_)            // 576

typedef __attribute__((ext_vector_type(8))) short short8_t;
typedef __attribute__((ext_vector_type(4))) float f32x4;

static __device__ __forceinline__ float bf2f(unsigned short u) {
  union { unsigned int i; float f; } v; v.i = ((unsigned int)u) << 16; return v.f;
}
static __device__ __forceinline__ unsigned short f2bf(float f) {
  union { float f; unsigned int i; } v; v.f = f;
  unsigned int r = v.i + 0x7FFF + ((v.i >> 16) & 1);   // RNE
  return (unsigned short)(r >> 16);
}

// async global->LDS, 16B per lane; lds base wave-uniform, lanes fill +lane*16
static __device__ __forceinline__ void gload_lds16(const void* g, void* l) {
  __builtin_amdgcn_global_load_lds(
      (const __attribute__((address_space(1))) unsigned int*)g,
      (__attribute__((address_space(3))) unsigned int*)l, 16, 0, 0);
}

// All 4 weight tensors [co][ci][kk] fp32 -> A2 chunk layout (16B chunk = 8
// consecutive k for one co): A2[((k>>3)*64+co)*8 + (k&7)], k = kk*64+ci.
// Also zeroes the 1KB zeropage.
__global__ __launch_bounds__(256) void prep_w_all(const float* __restrict__ w0,
                                                  const float* __restrict__ w1,
                                                  const float* __restrict__ w2,
                                                  const float* __restrict__ w3,
                                                  unsigned short* __restrict__ A2,
                                                  float* __restrict__ ZPf) {
  if (blockIdx.y == 0 && blockIdx.x == 0) ZPf[threadIdx.x] = 0.f;  // 1KB zeropage
  int idx = blockIdx.x * 256 + threadIdx.x;
  if (idx >= C_ * KDIM_) return;
  int which = blockIdx.y;
  const float* w = (which == 0) ? w0 : (which == 1) ? w1 : (which == 2) ? w2 : w3;
  unsigned short* out = A2 + (size_t)which * (C_ * KDIM_);
  int co = idx / KDIM_, k = idx % KDIM_;
  int ci = k & 63, kk = k >> 6;
  out[((size_t)(k >> 3) * 64 + co) * 8 + (k & 7)] =
      f2bf(w[((size_t)co * C_ + ci) * K_ + kk]);
}

// fp32 NCHW -> bf16 ci-minor [b][h][w][ci]
__global__ __launch_bounds__(256) void transpose_in(const float* __restrict__ x,
                                                    unsigned short* __restrict__ Xt) {
  __shared__ float tile[64][65];
  const int w0 = blockIdx.x * 64, h = blockIdx.y, b = blockIdx.z;
  const int t = threadIdx.x;
#pragma unroll
  for (int rep = 0; rep < 16; ++rep) {
    int idx = rep * 256 + t;
    int ci = idx >> 6, wl = idx & 63;
    tile[ci][wl] = x[((size_t)(b * C_ + ci) * H_ + h) * W_ + w0 + wl];
  }
  __syncthreads();
#pragma unroll
  for (int rep = 0; rep < 8; ++rep) {
    int idx = rep * 256 + t;
    int wl = idx >> 5, cp = idx & 31;
    unsigned v = (unsigned)f2bf(tile[cp*2][wl]) | ((unsigned)f2bf(tile[cp*2+1][wl]) << 16);
    *(unsigned*)(Xt + ((size_t)(b * H_ + h) * W_ + w0 + wl) * C_ + cp * 2) = v;
  }
}

// [b][w][h][ci] bf16 -> fp32 NCHW (final output, after the layout flip)
__global__ __launch_bounds__(256) void transpose_out_wh(const unsigned short* __restrict__ F,
                                                        float* __restrict__ out) {
  __shared__ float tile[64][65];   // [wl][ci]
  const int w0 = blockIdx.x * 64, h = blockIdx.y, b = blockIdx.z;
  const int t = threadIdx.x;
#pragma unroll
  for (int rep = 0; rep < 4; ++rep) {
    int idx = rep * 256 + t;
    int cp = idx & 15, wl = idx >> 4;
    uint2 v = *(const uint2*)(F + ((size_t)(b * W_ + w0 + wl) * H_ + h) * C_ + cp * 4);
    tile[wl][cp*4+0] = bf2f((unsigned short)v.x);
    tile[wl][cp*4+1] = bf2f((unsigned short)(v.x >> 16));
    tile[wl][cp*4+2] = bf2f((unsigned short)v.y);
    tile[wl][cp*4+3] = bf2f((unsigned short)(v.y >> 16));
  }
  __syncthreads();
#pragma unroll
  for (int rep = 0; rep < 16; ++rep) {
    int idx = rep * 256 + t;
    int ci = idx >> 6, wl = idx & 63;
    out[((size_t)(b * C_ + ci) * H_ + h) * W_ + w0 + wl] = tile[wl][ci];
  }
}

// ===== conv7: square-tile MFMA conv on [b][R][Q][ci], conv along Q =====
// conv6 + counted-vmcnt raw barrier (T4): per-iter barrier waits only for the
// wave's stage(t+1) loads (vmcnt(16): the 16 newest VMEM ops are this wave's
// epilogue stores, issued after its stage loads; in-order retirement => all
// stage loads landed) — epilogue stores are NOT drained, removing the
// per-supertile vmcnt(0) store-drain stall. Race-safety: barrier-at-end means
// all waves finished compute(t-1) before any wave issues stage(t+1) (WAR ok).
template<int QLEN>
__global__ __launch_bounds__(256, 1) void conv7(const unsigned short* __restrict__ X,
                                                unsigned short* __restrict__ Y,
                                                const unsigned short* __restrict__ A2,
                                                const float* __restrict__ bias,
                                                const unsigned short* __restrict__ ZP) {
  constexpr int SEGROWS = 256 / QLEN;              // 1 or 2 strips
  constexpr int NG      = (256 + 8 * SEGROWS) / 8; // 33 or 34 groups of 1KB
  __shared__ __align__(16) char lds[73728 + 2 * 34816];
  char* Alds  = lds;
  char* xbuf0 = lds + 73728;
  char* xbuf1 = lds + 73728 + 34816;

  const int t = threadIdx.x;
  const int lane = t & 63, wv = t >> 6;
  const int llo = lane & 15, lhi = lane >> 4;

  // ---- A -> LDS: 72 x 1KB groups, 18 per wave ----
#pragma unroll
  for (int i = 0; i < 18; ++i) {
    int m = wv + i * 4;
    gload_lds16(A2 + (size_t)m * 512 + lane * 8, Alds + m * 1024);
  }

  // stage super-tile u into dst
  auto stageX = [&](char* dst, int u) {
#pragma unroll
    for (int i = 0; i < 9; ++i) {
      int gl = wv + i * 4;
      if (gl < NG) {
        int strip = (SEGROWS == 2 && gl >= 17) ? 1 : 0;
        int gg = gl - strip * 17;
        int r = gg * 8 + (lane >> 3);            // row within strip
        int slot = lane & 7;
        int chunk = slot ^ (r & 7);
        int q = r - 4;
        int rowId = (SEGROWS == 1) ? u : u * 2 + strip;
        const void* src = ((unsigned)q < (unsigned)QLEN)
            ? (const void*)(X + (size_t)rowId * (QLEN * 64) + (size_t)q * 64 + chunk * 8)
            : (const void*)(ZP + slot * 8);
        gload_lds16(src, dst + strip * 17408 + gg * 1024);
      }
    }
  };

  float4 bv[4];
#pragma unroll
  for (int j = 0; j < 4; ++j) bv[j] = *(const float4*)(bias + j * 16 + lhi * 4);

  const int stripoff = (SEGROWS == 1) ? 0 : (wv >> 1) * 17408;
  const int posbase  = (SEGROWS == 1) ? wv * 64 : (wv & 1) * 64;

  const int u0 = blockIdx.x * 8;
  stageX(xbuf0, u0);
  __syncthreads();   // full drain once: A + stage(0)

  for (int tt = 0; tt < 8; ++tt) {
    const int u = u0 + tt;
    char* cur = (tt & 1) ? xbuf1 : xbuf0;
    char* nxt = (tt & 1) ? xbuf0 : xbuf1;
    if (tt < 7) stageX(nxt, u + 1);              // issue BEFORE compute

    const char* xb = cur + stripoff;
    f32x4 acc[4][4];
#pragma unroll
    for (int i = 0; i < 4; ++i)
#pragma unroll
      for (int j = 0; j < 4; ++j) { f32x4 z = {0.f,0.f,0.f,0.f}; acc[i][j] = z; }

#pragma unroll
    for (int step = 0; step < 18; ++step) {
      const int kk = step >> 1;
      const int cg = (step & 1) * 4 + lhi;
      short8_t a[4], f[4];
#pragma unroll
      for (int j = 0; j < 4; ++j)
        a[j] = *(const short8_t*)(Alds + step * 4096 + lhi * 1024 + j * 256 + llo * 16);
#pragma unroll
      for (int i = 0; i < 4; ++i) {
        int r = posbase + i * 16 + llo + kk;
        f[i] = *(const short8_t*)(xb + r * 128 + ((cg ^ (r & 7)) << 4));
      }
#pragma unroll
      for (int i = 0; i < 4; ++i)
#pragma unroll
        for (int j = 0; j < 4; ++j)
          acc[i][j] = __builtin_amdgcn_mfma_f32_16x16x32_bf16(a[j], f[i], acc[i][j], 0, 0, 0);
    }

    // epilogue: +bias, pack 4 consecutive co, 8B stores (16 per wave)
    const int outRow = (SEGROWS == 1) ? u : u * 2 + (wv >> 1);
    const size_t rowbase = (size_t)outRow * (QLEN * 64);
#pragma unroll
    for (int j = 0; j < 4; ++j) {
#pragma unroll
      for (int i = 0; i < 4; ++i) {
        const int q = posbase + i * 16 + llo;
        float v0 = acc[i][j][0] + bv[j].x;
        float v1 = acc[i][j][1] + bv[j].y;
        float v2 = acc[i][j][2] + bv[j].z;
        float v3 = acc[i][j][3] + bv[j].w;
        unsigned lo, hi;
        asm("v_cvt_pk_bf16_f32 %0, %1, %2" : "=v"(lo) : "v"(v0), "v"(v1));
        asm("v_cvt_pk_bf16_f32 %0, %1, %2" : "=v"(hi) : "v"(v2), "v"(v3));
        uint2 ov; ov.x = lo; ov.y = hi;
        *(uint2*)(Y + rowbase + (size_t)q * 64 + j * 16 + lhi * 4) = ov;
      }
    }
    if (tt < 7) {
      // counted barrier: retire this wave's stage(t+1) loads (older than the
      // 16 stores just issued); stores stay in flight across the barrier.
      asm volatile("s_waitcnt vmcnt(16)\n\ts_barrier" ::: "memory");
    }
  }
}

// ===== scan along OUTER dim P of [b][P][Q][ci], 4 ci/thread, depth-16 =====
// TRANS=1: write result transposed to [b][Q][P][ci] (outT) instead of in-place.
template<int PLEN, int QLEN, int REV, int TRANS>
__global__ __launch_bounds__(128) void scan_o4(unsigned short* __restrict__ conv,
                                               const unsigned short* __restrict__ prev,
                                               unsigned short* __restrict__ outT) {
  int idx = blockIdx.x * 128 + threadIdx.x;     // B * QLEN * 16
  int cq = idx & 15;
  int q  = (idx >> 4) % QLEN;
  int b  = idx / (16 * QLEN);
  const ptrdiff_t dp = (REV ? -1 : 1) * (ptrdiff_t)(QLEN * 64);
  const int p0 = REV ? PLEN - 1 : 0;
  size_t off = ((size_t)(b * PLEN + p0) * QLEN + q) * 64 + cq * 4;
  size_t offT = 0; ptrdiff_t dpT = 0;
  if (TRANS) {
    offT = ((size_t)(b * QLEN + q) * PLEN + p0) * 64 + cq * 4;
    dpT = (REV ? -1 : 1) * (ptrdiff_t)64;
  }
  uint2 pv = *(const uint2*)(prev + off);
  if (TRANS) *(uint2*)(outT + offT) = pv; else *(uint2*)(conv + off) = pv;
  float y0 = bf2f((unsigned short)pv.x), y1 = bf2f((unsigned short)(pv.x >> 16));
  float y2 = bf2f((unsigned short)pv.y), y3 = bf2f((unsigned short)(pv.y >> 16));
  uint2 c[16];
#pragma unroll
  for (int j = 0; j < 16; ++j) c[j] = *(const uint2*)(conv + off + (ptrdiff_t)(j + 1) * dp);
  for (int base = 1; base < PLEN; base += 16) {
#pragma unroll
    for (int j = 0; j < 16; ++j) {
      int s = base + j;
      if (s < PLEN) {
        off += dp;
        if (TRANS) offT += dpT;
        y0 = fmaxf(bf2f((unsigned short)c[j].x) + y0, 0.f);
        y1 = fmaxf(bf2f((unsigned short)(c[j].x >> 16)) + y1, 0.f);
        y2 = fmaxf(bf2f((unsigned short)c[j].y) + y2, 0.f);
        y3 = fmaxf(bf2f((unsigned short)(c[j].y >> 16)) + y3, 0.f);
        uint2 ov;
        ov.x = (unsigned)f2bf(y0) | ((unsigned)f2bf(y1) << 16);
        ov.y = (unsigned)f2bf(y2) | ((unsigned)f2bf(y3) << 16);
        if (TRANS) *(uint2*)(outT + offT) = ov; else *(uint2*)(conv + off) = ov;
        if (s + 16 < PLEN) c[j] = *(const uint2*)(conv + off + 16 * dp);
      }
    }
  }
}

// ===== scan_o2: same scan, 2 ci/thread (uint) — doubles wave count for the
// QLEN=128 sweeps (3/4), whose 4-ci version had only 1 wave/SIMD. Depth-16.
template<int PLEN, int QLEN, int REV>
__global__ __launch_bounds__(128) void scan_o2(unsigned short* __restrict__ conv,
                                               const unsigned short* __restrict__ prev) {
  int idx = blockIdx.x * 128 + threadIdx.x;     // B * QLEN * 32
  int cp = idx & 31;
  int q  = (idx >> 5) % QLEN;
  int b  = idx / (32 * QLEN);
  const ptrdiff_t dp = (REV ? -1 : 1) * (ptrdiff_t)(QLEN * 64);
  const int p0 = REV ? PLEN - 1 : 0;
  size_t off = ((size_t)(b * PLEN + p0) * QLEN + q) * 64 + cp * 2;
  unsigned pv = *(const unsigned*)(prev + off);
  *(unsigned*)(conv + off) = pv;
  float y0 = bf2f((unsigned short)pv), y1 = bf2f((unsigned short)(pv >> 16));
  unsigned c[16];
#pragma unroll
  for (int j = 0; j < 16; ++j) c[j] = *(const unsigned*)(conv + off + (ptrdiff_t)(j + 1) * dp);
  for (int base = 1; base < PLEN; base += 16) {
#pragma unroll
    for (int j = 0; j < 16; ++j) {
      int s = base + j;
      if (s < PLEN) {
        off += dp;
        y0 = fmaxf(bf2f((unsigned short)c[j]) + y0, 0.f);
        y1 = fmaxf(bf2f((unsigned short)(c[j] >> 16)) + y1, 0.f);
        *(unsigned*)(conv + off) = (unsigned)f2bf(y0) | ((unsigned)f2bf(y1) << 16);
        if (s + 16 < PLEN) c[j] = *(const unsigned*)(conv + off + 16 * dp);
      }
    }
  }
}

extern "C" void kernel_launch(void* const* d_in, const int* in_sizes, int n_in,
                              void* d_out, int out_size, void* d_ws, size_t ws_size,
                              hipStream_t stream) {
  const float* x    = (const float*)d_in[0];
  const float* w_ud = (const float*)d_in[1];
  const float* b_ud = (const float*)d_in[2];
  const float* w_du = (const float*)d_in[3];
  const float* b_du = (const float*)d_in[4];
  const float* w_lr = (const float*)d_in[5];
  const float* b_lr = (const float*)d_in[6];
  const float* w_rl = (const float*)d_in[7];
  const float* b_rl = (const float*)d_in[8];

  // ws: A[0,64M) Bb[64M,128M) Cc[128M,192M) A2 @192M, zeropage @192M+1M
  unsigned short* A  = (unsigned short*)d_ws;
  unsigned short* Bb = (unsigned short*)((char*)d_ws + 67108864);
  unsigned short* Cc = (unsigned short*)((char*)d_ws + 134217728);
  unsigned short* A2 = (unsigned short*)((char*)d_ws + 201326592);
  unsigned short* ZP = (unsigned short*)((char*)d_ws + 202375168);
  unsigned short* A2_ud = A2 + 0 * (C_ * KDIM_);
  unsigned short* A2_du = A2 + 1 * (C_ * KDIM_);
  unsigned short* A2_lr = A2 + 2 * (C_ * KDIM_);
  unsigned short* A2_rl = A2 + 3 * (C_ * KDIM_);

  dim3 pg((C_ * KDIM_ + 255) / 256, 4);
  prep_w_all<<<pg, 256, 0, stream>>>(w_ud, w_du, w_lr, w_rl, A2, (float*)ZP);

  transpose_in<<<dim3(4, H_, B_), 256, 0, stream>>>(x, A);

  // sweep 1 (ud): conv along W on [b][h][w][ci]; scan fwd along h
  conv7<W_><<<256, 256, 0, stream>>>(A, Bb, A2_ud, b_ud, ZP);
  scan_o4<H_, W_, 0, 0><<<512, 128, 0, stream>>>(Bb, A, nullptr);

  // sweep 2 (du): conv along W; scan rev along h, WRITE TRANSPOSED -> [b][w][h][ci]
  conv7<W_><<<256, 256, 0, stream>>>(Bb, Cc, A2_du, b_du, ZP);
  scan_o4<H_, W_, 1, 1><<<512, 128, 0, stream>>>(Cc, Bb, A);

  // sweep 3 (lr): conv along H (inner dim of flipped layout); scan fwd along w
  conv7<H_><<<256, 256, 0, stream>>>(A, Bb, A2_lr, b_lr, ZP);
  scan_o2<W_, H_, 0><<<512, 128, 0, stream>>>(Bb, A);

  // sweep 4 (rl): conv along H; scan rev along w
  conv7<H_><<<256, 256, 0, stream>>>(Bb, Cc, A2_rl, b_rl, ZP);
  scan_o2<W_, H_, 1><<<512, 128, 0, stream>>>(Cc, Bb);

  transpose_out_wh<<<dim3(4, H_, B_), 256, 0, stream>>>(Cc, (float*)d_out);
}